// Round 8
// baseline (206.636 us; speedup 1.0000x reference)
//
#include <hip/hip_runtime.h>
#include <hip/hip_bf16.h>
#include <cstdint>

#define B_   4
#define T_   2048
#define C_   1024
#define H_   16
#define D_   64
#define TC3  3072
#define M_   (B_ * T_)   // 8192

typedef short  bf16x8 __attribute__((ext_vector_type(8)));
typedef short  bf16x4 __attribute__((ext_vector_type(4)));
typedef float  f32x4  __attribute__((ext_vector_type(4)));

#define AS1(p) ((const __attribute__((address_space(1))) void*)(p))
#define AS3(p) ((__attribute__((address_space(3))) void*)(p))

__device__ inline float bf2f(unsigned short u) {
    union { unsigned int i; float f; } x; x.i = ((unsigned int)u) << 16; return x.f;
}
__device__ inline unsigned short f2bf(float f) {
    union { float f; unsigned int i; } x; x.f = f;
    return (unsigned short)((x.i + 0x7fffu + ((x.i >> 16) & 1u)) >> 16);
}
// pack two f32 -> one u32 of 2 bf16 (lo = a, hi = b)
__device__ inline unsigned int cvtpk_bf16(float a, float b) {
    unsigned int r;
    asm("v_cvt_pk_bf16_f32 %0, %1, %2" : "=v"(r) : "v"(a), "v"(b));
    return r;
}
// D = A(16x16 bf16 rows=q, k=lhi*4+j) * B(cols=d, k)^T + C   (K=16 MFMA)
__device__ inline f32x4 mfma16x16x16(bf16x4 a, bf16x4 b, f32x4 c) {
#if __has_builtin(__builtin_amdgcn_mfma_f32_16x16x16bf16_1k)
    return __builtin_amdgcn_mfma_f32_16x16x16bf16_1k(a, b, c, 0, 0, 0);
#else
    asm("v_mfma_f32_16x16x16_bf16 %0, %1, %2, %0" : "+v"(c) : "v"(a), "v"(b));
    return c;
#endif
}

// ---------------- cast f32 -> bf16, 8 elements/thread ----------------
__global__ void cast_f32_bf16(const float* __restrict__ in,
                              unsigned short* __restrict__ out) {
    const size_t i = ((size_t)blockIdx.x * blockDim.x + threadIdx.x) * 8;
    f32x4 a = *(const f32x4*)(in + i);
    f32x4 b = *(const f32x4*)(in + i + 4);
    bf16x8 o;
#pragma unroll
    for (int j = 0; j < 4; ++j) { o[j] = (short)f2bf(a[j]); o[4 + j] = (short)f2bf(b[j]); }
    *(bf16x8*)(out + i) = o;
}

// ---------------- transpose + cast: in[R][C] f32 -> out[C][R] bf16 ----------------
__global__ void transpose_cast(const float* __restrict__ in,
                               unsigned short* __restrict__ out, int R, int C) {
    __shared__ unsigned short tile[32][33];
    const int bc = blockIdx.x * 32, br = blockIdx.y * 32;
    const int tx = threadIdx.x & 31, ty = threadIdx.x >> 5;
#pragma unroll
    for (int i = 0; i < 4; ++i) {
        int r = ty + i * 8;
        tile[r][tx] = f2bf(in[(size_t)(br + r) * C + bc + tx]);
    }
    __syncthreads();
#pragma unroll
    for (int i = 0; i < 4; ++i) {
        int r = ty + i * 8;
        out[(size_t)(bc + r) * R + br + tx] = tile[tx][r];
    }
}

// ------------- GEMM: C[M][N] = A[M][K] * Bt[N][K]^T + bias[N] (bf16 in, f32 acc) -------------
template <bool OUTF32>
__global__ __launch_bounds__(256, 2) void gemm_bt_bias(
    const unsigned short* __restrict__ A, const unsigned short* __restrict__ Bt,
    const float* __restrict__ bias, void* __restrict__ Cout,
    int M, int N, int K) {
    __shared__ unsigned short As[128 * 32];
    __shared__ unsigned short Bs[128 * 32];
    const int tid = threadIdx.x;
    const int wave = tid >> 6, lane = tid & 63;
    const int m0 = blockIdx.x * 128, n0 = blockIdx.y * 128;
    const int wr = (wave >> 1) * 64, wc = (wave & 1) * 64;

    f32x4 acc[4][4] = {};

    const int srow = (lane >> 2);
    const int scol = (lane & 3) * 8;

    for (int k0 = 0; k0 < K; k0 += 32) {
#pragma unroll
        for (int j = 0; j < 2; ++j) {
            const int chunk = wave * 2 + j;
            const int row = chunk * 16 + srow;
            __builtin_amdgcn_global_load_lds(
                AS1(A + (size_t)(m0 + row) * K + k0 + scol),
                AS3(As + chunk * 512), 16, 0, 0);
            __builtin_amdgcn_global_load_lds(
                AS1(Bt + (size_t)(n0 + row) * K + k0 + scol),
                AS3(Bs + chunk * 512), 16, 0, 0);
        }
        __syncthreads();
        bf16x8 a[4], b[4];
#pragma unroll
        for (int i = 0; i < 4; ++i)
            a[i] = *(const bf16x8*)&As[(wr + i * 16 + (lane & 15)) * 32 + (lane >> 4) * 8];
#pragma unroll
        for (int i = 0; i < 4; ++i)
            b[i] = *(const bf16x8*)&Bs[(wc + i * 16 + (lane & 15)) * 32 + (lane >> 4) * 8];
        __builtin_amdgcn_s_setprio(1);
#pragma unroll
        for (int i = 0; i < 4; ++i)
#pragma unroll
            for (int j = 0; j < 4; ++j)
                acc[i][j] = __builtin_amdgcn_mfma_f32_16x16x32_bf16(a[i], b[j], acc[i][j], 0, 0, 0);
        __builtin_amdgcn_s_setprio(0);
        __syncthreads();
    }

#pragma unroll
    for (int i = 0; i < 4; ++i) {
        const int rowb = m0 + wr + i * 16 + (lane >> 4) * 4;
#pragma unroll
        for (int j = 0; j < 4; ++j) {
            const int col = n0 + wc + j * 16 + (lane & 15);
            const float bv = bias[col];
#pragma unroll
            for (int r = 0; r < 4; ++r) {
                const float v = acc[i][j][r] + bv;
                if (OUTF32)
                    ((float*)Cout)[(size_t)(rowb + r) * N + col] = v;
                else
                    ((unsigned short*)Cout)[(size_t)(rowb + r) * N + col] = f2bf(v);
            }
        }
    }
}

// ------------- causal flash attention (swapped-QK, in-register softmax, KVBLK=128) -------------
// grid: (B*H, 8). Block (bh, pr) handles strips tq=pr and 15-pr (uniform
// 17 x 128-wide kv tiles). 8 waves x 16 q-rows, 512 threads, 2 blocks/CU.
// s = mfma(K, Q): lane(l15,lhi) holds S[q=q0+l15][k=kv0+kt*16+lhi*4+r],
// kt=0..7. Softmax lane-local; P stays in registers as 16x16x16 A-frags.
// K LDS [128][72]; V^T LDS [64][136] (stride 68 words = 4 mod 32), col
// swizzle k ^ 8*(d>>3). T14 async staging.
__global__ __launch_bounds__(512, 4) void attn_kernel(
    const unsigned short* __restrict__ QKV, unsigned short* __restrict__ Y) {
    __shared__ unsigned short Kl[128][72];
    __shared__ unsigned short Vt[64][136];

    const int tid = threadIdx.x, wave = tid >> 6, lane = tid & 63;
    const int bh = blockIdx.x;           // XCD = bh & 7 -> pair-blocks share L2
    const int pr = blockIdx.y;           // 0..7
    const int b = bh >> 4, h = bh & 15;
    const size_t rowbase = (size_t)b * T_ * TC3;
    const int l15 = lane & 15, lhi = lane >> 4;
    const int srow = tid >> 3;           // 0..63 (this thread stages kv rows srow, srow+64)
    const int sseg = tid & 7;            // 0..7  (d segment)

    for (int sp = 0; sp < 2; ++sp) {
        const int tq = sp ? (15 - pr) : pr;
        const int q0 = tq * 128 + wave * 16;
        const int ntiles = tq + 1;
        const int qv = q0 + l15;         // this lane's softmax row

        // Q fragments, pre-scaled by 1/sqrt(D) * log2(e)
        bf16x8 qf[2];
        {
            const unsigned short* p =
                QKV + rowbase + (size_t)(q0 + l15) * TC3 + h * 64 + lhi * 8;
            qf[0] = *(const bf16x8*)p;
            qf[1] = *(const bf16x8*)(p + 32);
#pragma unroll
            for (int hf = 0; hf < 2; ++hf)
#pragma unroll
                for (int j = 0; j < 8; ++j)
                    qf[hf][j] = (short)f2bf(bf2f((unsigned short)qf[hf][j]) * 0.18033688011f);
        }

        float m2 = -1e30f, l_run = 0.f;
        f32x4 o[4] = {};

        __syncthreads();   // previous strip's LDS use complete
        // prologue: stage tile 0 (2 K-rows + 2 V-rows per thread)
        {
            const unsigned short* src =
                QKV + rowbase + (size_t)srow * TC3 + C_ + h * 64 + sseg * 8;
            bf16x8 ka = *(const bf16x8*)src;
            bf16x8 kb = *(const bf16x8*)(src + (size_t)64 * TC3);
            bf16x8 va = *(const bf16x8*)(src + C_);
            bf16x8 vb = *(const bf16x8*)(src + C_ + (size_t)64 * TC3);
            *(bf16x8*)&Kl[srow][sseg * 8] = ka;
            *(bf16x8*)&Kl[srow + 64][sseg * 8] = kb;
            const int swz = srow ^ (sseg << 3);
#pragma unroll
            for (int j = 0; j < 8; ++j) {
                Vt[sseg * 8 + j][swz] = (unsigned short)va[j];
                Vt[sseg * 8 + j][swz + 64] = (unsigned short)vb[j];
            }
        }

        for (int t = 0; t < ntiles; ++t) {
            const int kv0 = t * 128;
            __syncthreads();   // staged tile t visible

            // T14: issue next tile's loads now, LDS-write after tail barrier
            bf16x8 pka, pkb, pva, pvb;
            const bool pf_valid = (t + 1 < ntiles);
            if (pf_valid) {
                const unsigned short* src =
                    QKV + rowbase + (size_t)(kv0 + 128 + srow) * TC3 + C_ + h * 64 + sseg * 8;
                pka = *(const bf16x8*)src;
                pkb = *(const bf16x8*)(src + (size_t)64 * TC3);
                pva = *(const bf16x8*)(src + C_);
                pvb = *(const bf16x8*)(src + C_ + (size_t)64 * TC3);
            }

            // S^T tile: mfma(A=K, B=Q) -> lane: q=qv, k=kv0+kt*16+lhi*4+r
            f32x4 s[8];
            __builtin_amdgcn_s_setprio(1);
#pragma unroll
            for (int kt = 0; kt < 8; ++kt) {
                bf16x8 kf0 = *(const bf16x8*)&Kl[kt * 16 + l15][lhi * 8];
                bf16x8 kf1 = *(const bf16x8*)&Kl[kt * 16 + l15][32 + lhi * 8];
                f32x4 acc = {};
                acc = __builtin_amdgcn_mfma_f32_16x16x32_bf16(kf0, qf[0], acc, 0, 0, 0);
                acc = __builtin_amdgcn_mfma_f32_16x16x32_bf16(kf1, qf[1], acc, 0, 0, 0);
                s[kt] = acc;
            }
            __builtin_amdgcn_s_setprio(0);

            const bool needmask = (kv0 + 127 > q0);
            if (needmask) {
#pragma unroll
                for (int kt = 0; kt < 8; ++kt) {
                    const int kb = kv0 + kt * 16 + lhi * 4;
#pragma unroll
                    for (int r = 0; r < 4; ++r)
                        s[kt][r] = (kb + r <= qv) ? s[kt][r] : -1e30f;
                }
            }
            // row max: in-lane tree + 2 shfl (cross k-quarter)
            f32x4 vm;
#pragma unroll
            for (int r = 0; r < 4; ++r) {
                float a0 = fmaxf(fmaxf(s[0][r], s[1][r]), fmaxf(s[2][r], s[3][r]));
                float a1 = fmaxf(fmaxf(s[4][r], s[5][r]), fmaxf(s[6][r], s[7][r]));
                vm[r] = fmaxf(a0, a1);
            }
            float tmax = fmaxf(fmaxf(vm[0], vm[1]), fmaxf(vm[2], vm[3]));
            tmax = fmaxf(tmax, __shfl_xor(tmax, 16, 64));
            tmax = fmaxf(tmax, __shfl_xor(tmax, 32, 64));

            // defer-max (T13), threshold 8 nats = 11.54 bits
            if (__any(tmax > m2 + 11.5416f)) {
                const float mnew = fmaxf(m2, tmax);
                const float corr = exp2f(m2 - mnew);
                m2 = mnew; l_run *= corr;
                float cq[4];
#pragma unroll
                for (int r = 0; r < 4; ++r)
                    cq[r] = __shfl(corr, lhi * 16 + lhi * 4 + r, 64);
#pragma unroll
                for (int dt = 0; dt < 4; ++dt)
#pragma unroll
                    for (int r = 0; r < 4; ++r) o[dt][r] *= cq[r];
            }
            // exp2 + row sum
#pragma unroll
            for (int kt = 0; kt < 8; ++kt)
#pragma unroll
                for (int r = 0; r < 4; ++r)
                    s[kt][r] = exp2f(s[kt][r] - m2);
            {
                f32x4 vs;
#pragma unroll
                for (int r = 0; r < 4; ++r)
                    vs[r] = ((s[0][r] + s[1][r]) + (s[2][r] + s[3][r])) +
                            ((s[4][r] + s[5][r]) + (s[6][r] + s[7][r]));
                float tsum = (vs[0] + vs[1]) + (vs[2] + vs[3]);
                tsum += __shfl_xor(tsum, 16, 64);
                tsum += __shfl_xor(tsum, 32, 64);
                l_run += tsum;
            }
            // pack P into 16x16x16 A-frags (k = lhi*4 + j)
            bf16x4 pa[8];
#pragma unroll
            for (int kt = 0; kt < 8; ++kt) {
                unsigned int pw[2];
                pw[0] = cvtpk_bf16(s[kt][0], s[kt][1]);
                pw[1] = cvtpk_bf16(s[kt][2], s[kt][3]);
                pa[kt] = *(const bf16x4*)pw;
            }

            // PV: O += P * V  (32 x K=16 MFMA; B = Vt 8B reads)
            __builtin_amdgcn_s_setprio(1);
#pragma unroll
            for (int dt = 0; dt < 4; ++dt) {
                const int d = dt * 16 + l15;
                const int xs = (d >> 3) << 3;
#pragma unroll
                for (int kt = 0; kt < 8; ++kt) {
                    bf16x4 vb = *(const bf16x4*)&Vt[d][(kt * 16 + lhi * 4) ^ xs];
                    o[dt] = mfma16x16x16(pa[kt], vb, o[dt]);
                }
            }
            __builtin_amdgcn_s_setprio(0);

            __syncthreads();   // all reads of tile t complete
            if (pf_valid) {
                *(bf16x8*)&Kl[srow][sseg * 8] = pka;
                *(bf16x8*)&Kl[srow + 64][sseg * 8] = pkb;
                const int swz = srow ^ (sseg << 3);
#pragma unroll
                for (int j = 0; j < 8; ++j) {
                    Vt[sseg * 8 + j][swz] = (unsigned short)pva[j];
                    Vt[sseg * 8 + j][swz + 64] = (unsigned short)pvb[j];
                }
            }
        }

        // epilogue: fetch l for q = q0 + lhi*4 + r, divide, store
        float rq[4];
#pragma unroll
        for (int r = 0; r < 4; ++r) {
            const float lq = __shfl(l_run, lhi * 16 + lhi * 4 + r, 64);
            rq[r] = 1.0f / lq;
        }
#pragma unroll
        for (int dt = 0; dt < 4; ++dt)
#pragma unroll
            for (int r = 0; r < 4; ++r) {
                const int q = q0 + lhi * 4 + r;
                const int d = dt * 16 + l15;
                Y[((size_t)b * T_ + q) * C_ + h * 64 + d] = f2bf(o[dt][r] * rq[r]);
            }
    }
}

extern "C" void kernel_launch(void* const* d_in, const int* in_sizes, int n_in,
                              void* d_out, int out_size, void* d_ws, size_t ws_size,
                              hipStream_t stream) {
    const float* x     = (const float*)d_in[0];
    const float* Wqkv  = (const float*)d_in[1];
    const float* bqkv  = (const float*)d_in[2];
    const float* Wproj = (const float*)d_in[3];
    const float* bproj = (const float*)d_in[4];
    float* out = (float*)d_out;

    char* ws = (char*)d_ws;
    unsigned short* qkv    = (unsigned short*)(ws);                          // 8192x3072 bf16
    unsigned short* yat    = (unsigned short*)(ws + 50331648);               // 8192x1024 bf16
    unsigned short* WqkvT  = (unsigned short*)(ws + 67108864);               // 3072x1024 bf16
    unsigned short* WprojT = (unsigned short*)(ws + 73400320);               // 1024x1024 bf16
    unsigned short* xb     = (unsigned short*)(ws + 75497472);               // 8192x1024 bf16

    cast_f32_bf16<<<dim3((M_ * C_) / (256 * 8)), dim3(256), 0, stream>>>(x, xb);
    transpose_cast<<<dim3(TC3 / 32, C_ / 32), dim3(256), 0, stream>>>(Wqkv, WqkvT, C_, TC3);
    transpose_cast<<<dim3(C_ / 32, C_ / 32), dim3(256), 0, stream>>>(Wproj, WprojT, C_, C_);
    gemm_bt_bias<false><<<dim3(M_ / 128, TC3 / 128), dim3(256), 0, stream>>>(xb, WqkvT, bqkv, qkv, M_, TC3, C_);
    attn_kernel<<<dim3(B_ * H_, 8), dim3(512), 0, stream>>>(qkv, yat);
    gemm_bt_bias<true><<<dim3(M_ / 128, C_ / 128), dim3(256), 0, stream>>>(yat, WprojT, bproj, out, M_, C_, C_);
}

// Round 9
// 181.808 us; speedup vs baseline: 1.1366x; 1.1366x over previous
//
#include <hip/hip_runtime.h>
#include <hip/hip_bf16.h>
#include <cstdint>

#define B_   4
#define T_   2048
#define C_   1024
#define H_   16
#define D_   64
#define TC3  3072
#define M_   (B_ * T_)   // 8192

typedef short  bf16x8 __attribute__((ext_vector_type(8)));
typedef short  bf16x4 __attribute__((ext_vector_type(4)));
typedef float  f32x4  __attribute__((ext_vector_type(4)));

#define AS1(p) ((const __attribute__((address_space(1))) void*)(p))
#define AS3(p) ((__attribute__((address_space(3))) void*)(p))

__device__ inline float bf2f(unsigned short u) {
    union { unsigned int i; float f; } x; x.i = ((unsigned int)u) << 16; return x.f;
}
__device__ inline unsigned short f2bf(float f) {
    union { float f; unsigned int i; } x; x.f = f;
    return (unsigned short)((x.i + 0x7fffu + ((x.i >> 16) & 1u)) >> 16);
}
// pack two f32 -> one u32 of 2 bf16 (lo = a, hi = b)
__device__ inline unsigned int cvtpk_bf16(float a, float b) {
    unsigned int r;
    asm("v_cvt_pk_bf16_f32 %0, %1, %2" : "=v"(r) : "v"(a), "v"(b));
    return r;
}
// D = A(16x16 bf16 rows=q, k=lhi*4+j) * B(cols=d, k)^T + C   (K=16 MFMA)
__device__ inline f32x4 mfma16x16x16(bf16x4 a, bf16x4 b, f32x4 c) {
#if __has_builtin(__builtin_amdgcn_mfma_f32_16x16x16bf16_1k)
    return __builtin_amdgcn_mfma_f32_16x16x16bf16_1k(a, b, c, 0, 0, 0);
#else
    asm("v_mfma_f32_16x16x16_bf16 %0, %1, %2, %0" : "+v"(c) : "v"(a), "v"(b));
    return c;
#endif
}

// ---------------- cast f32 -> bf16, 8 elements/thread ----------------
__global__ void cast_f32_bf16(const float* __restrict__ in,
                              unsigned short* __restrict__ out) {
    const size_t i = ((size_t)blockIdx.x * blockDim.x + threadIdx.x) * 8;
    f32x4 a = *(const f32x4*)(in + i);
    f32x4 b = *(const f32x4*)(in + i + 4);
    bf16x8 o;
#pragma unroll
    for (int j = 0; j < 4; ++j) { o[j] = (short)f2bf(a[j]); o[4 + j] = (short)f2bf(b[j]); }
    *(bf16x8*)(out + i) = o;
}

// ---------------- transpose + cast: in[R][C] f32 -> out[C][R] bf16 ----------------
__global__ void transpose_cast(const float* __restrict__ in,
                               unsigned short* __restrict__ out, int R, int C) {
    __shared__ unsigned short tile[32][33];
    const int bc = blockIdx.x * 32, br = blockIdx.y * 32;
    const int tx = threadIdx.x & 31, ty = threadIdx.x >> 5;
#pragma unroll
    for (int i = 0; i < 4; ++i) {
        int r = ty + i * 8;
        tile[r][tx] = f2bf(in[(size_t)(br + r) * C + bc + tx]);
    }
    __syncthreads();
#pragma unroll
    for (int i = 0; i < 4; ++i) {
        int r = ty + i * 8;
        out[(size_t)(bc + r) * R + br + tx] = tile[tx][r];
    }
}

// ------------- GEMM: C[M][N] = A[M][K] * Bt[N][K]^T + bias[N] (bf16 in, f32 acc) -------------
// 128x128 tile, BK=64 with two-phase fragment reuse (halved barrier count vs
// BK=32; live fragments unchanged -> no VGPR growth). 4 waves (2x2).
template <bool OUTF32>
__global__ __launch_bounds__(256, 2) void gemm_bt_bias(
    const unsigned short* __restrict__ A, const unsigned short* __restrict__ Bt,
    const float* __restrict__ bias, void* __restrict__ Cout,
    int M, int N, int K) {
    __shared__ unsigned short As[128 * 64];
    __shared__ unsigned short Bs[128 * 64];
    const int tid = threadIdx.x;
    const int wave = tid >> 6, lane = tid & 63;
    const int m0 = blockIdx.x * 128, n0 = blockIdx.y * 128;
    const int wr = (wave >> 1) * 64, wc = (wave & 1) * 64;

    f32x4 acc[4][4] = {};

    const int srow = (lane >> 3);          // 0..7 within chunk
    const int scol = (lane & 7) * 8;       // element offset in K-slice

    for (int k0 = 0; k0 < K; k0 += 64) {
#pragma unroll
        for (int j = 0; j < 4; ++j) {
            const int chunk = wave * 4 + j;            // 0..15
            const int row = chunk * 8 + srow;
            __builtin_amdgcn_global_load_lds(
                AS1(A + (size_t)(m0 + row) * K + k0 + scol),
                AS3(As + chunk * 512), 16, 0, 0);
            __builtin_amdgcn_global_load_lds(
                AS1(Bt + (size_t)(n0 + row) * K + k0 + scol),
                AS3(Bs + chunk * 512), 16, 0, 0);
        }
        __syncthreads();
        // phase 0: k in [k0, k0+32)
        {
            bf16x8 a[4], b[4];
#pragma unroll
            for (int i = 0; i < 4; ++i)
                a[i] = *(const bf16x8*)&As[(wr + i * 16 + (lane & 15)) * 64 + (lane >> 4) * 8];
#pragma unroll
            for (int i = 0; i < 4; ++i)
                b[i] = *(const bf16x8*)&Bs[(wc + i * 16 + (lane & 15)) * 64 + (lane >> 4) * 8];
            __builtin_amdgcn_s_setprio(1);
#pragma unroll
            for (int i = 0; i < 4; ++i)
#pragma unroll
                for (int j = 0; j < 4; ++j)
                    acc[i][j] = __builtin_amdgcn_mfma_f32_16x16x32_bf16(a[i], b[j], acc[i][j], 0, 0, 0);
            __builtin_amdgcn_s_setprio(0);
        }
        // phase 1: k in [k0+32, k0+64)
        {
            bf16x8 a[4], b[4];
#pragma unroll
            for (int i = 0; i < 4; ++i)
                a[i] = *(const bf16x8*)&As[(wr + i * 16 + (lane & 15)) * 64 + 32 + (lane >> 4) * 8];
#pragma unroll
            for (int i = 0; i < 4; ++i)
                b[i] = *(const bf16x8*)&Bs[(wc + i * 16 + (lane & 15)) * 64 + 32 + (lane >> 4) * 8];
            __builtin_amdgcn_s_setprio(1);
#pragma unroll
            for (int i = 0; i < 4; ++i)
#pragma unroll
                for (int j = 0; j < 4; ++j)
                    acc[i][j] = __builtin_amdgcn_mfma_f32_16x16x32_bf16(a[i], b[j], acc[i][j], 0, 0, 0);
            __builtin_amdgcn_s_setprio(0);
        }
        __syncthreads();
    }

#pragma unroll
    for (int i = 0; i < 4; ++i) {
        const int rowb = m0 + wr + i * 16 + (lane >> 4) * 4;
#pragma unroll
        for (int j = 0; j < 4; ++j) {
            const int col = n0 + wc + j * 16 + (lane & 15);
            const float bv = bias[col];
#pragma unroll
            for (int r = 0; r < 4; ++r) {
                const float v = acc[i][j][r] + bv;
                if (OUTF32)
                    ((float*)Cout)[(size_t)(rowb + r) * N + col] = v;
                else
                    ((unsigned short*)Cout)[(size_t)(rowb + r) * N + col] = f2bf(v);
            }
        }
    }
}

// ------------- causal flash attention (swapped-QK, in-register softmax) -------------
// ROUND-7 VERIFIED KERNEL (90.6 us). grid: (B*H, 8). Block (bh, pr) handles
// strips tq=pr and 15-pr (uniform 34 tiles). 8 waves x 16 q-rows, 512
// threads, 2 blocks/CU. KVBLK=64. s = mfma(K, Q): lane(l15,lhi) holds
// S[q=q0+l15][k=kv0+kt*16+lhi*4+r]; softmax lane-local; P in registers as
// 16x16x16 A-frags. 56 VGPR, no spill — do NOT grow live state (round-8
// KVBLK=128 spilled: VGPR 64 + 100 MB scratch traffic).
__global__ __launch_bounds__(512, 4) void attn_kernel(
    const unsigned short* __restrict__ QKV, unsigned short* __restrict__ Y) {
    __shared__ unsigned short Kl[64][72];
    __shared__ unsigned short Vt[64][72];   // V^T, col swizzled: k ^ (8*(d>>3))

    const int tid = threadIdx.x, wave = tid >> 6, lane = tid & 63;
    const int bh = blockIdx.x;           // XCD = bh & 7 -> pair-blocks share L2
    const int pr = blockIdx.y;           // 0..7
    const int b = bh >> 4, h = bh & 15;
    const size_t rowbase = (size_t)b * T_ * TC3;
    const int l15 = lane & 15, lhi = lane >> 4;
    const int srow = tid >> 3;           // 0..63 (kv row)
    const int sseg = tid & 7;            // 0..7  (d segment)

    for (int sp = 0; sp < 2; ++sp) {
        const int tq = sp ? (15 - pr) : pr;
        const int qb = tq * 128;
        const int q0 = qb + wave * 16;
        const int ntiles = 2 * tq + 2;
        const int qv = q0 + l15;         // this lane's softmax row

        // Q fragments, pre-scaled by 1/sqrt(D) * log2(e)
        bf16x8 qf[2];
        {
            const unsigned short* p =
                QKV + rowbase + (size_t)(q0 + l15) * TC3 + h * 64 + lhi * 8;
            qf[0] = *(const bf16x8*)p;
            qf[1] = *(const bf16x8*)(p + 32);
#pragma unroll
            for (int hf = 0; hf < 2; ++hf)
#pragma unroll
                for (int j = 0; j < 8; ++j)
                    qf[hf][j] = (short)f2bf(bf2f((unsigned short)qf[hf][j]) * 0.18033688011f);
        }

        float m2 = -1e30f, l_run = 0.f;
        f32x4 o[4] = {};

        __syncthreads();   // previous strip's LDS use complete
        // prologue: stage tile 0 (1 K-row + 1 V-row per thread)
        {
            const unsigned short* src =
                QKV + rowbase + (size_t)srow * TC3 + C_ + h * 64 + sseg * 8;
            bf16x8 k8 = *(const bf16x8*)src;
            bf16x8 v8 = *(const bf16x8*)(src + C_);
            *(bf16x8*)&Kl[srow][sseg * 8] = k8;
            const int swz = srow ^ (sseg << 3);
#pragma unroll
            for (int j = 0; j < 8; ++j)
                Vt[sseg * 8 + j][swz] = (unsigned short)v8[j];
        }

        for (int t = 0; t < ntiles; ++t) {
            const int kv0 = t * 64;
            __syncthreads();   // staged tile t visible

            // T14: issue next tile's loads now, LDS-write after tail barrier
            bf16x8 pk8, pv8;
            const bool pf_valid = (t + 1 < ntiles);
            if (pf_valid) {
                const unsigned short* src =
                    QKV + rowbase + (size_t)(kv0 + 64 + srow) * TC3 + C_ + h * 64 + sseg * 8;
                pk8 = *(const bf16x8*)src;
                pv8 = *(const bf16x8*)(src + C_);
            }

            if (q0 + 15 >= kv0) {   // wave-tile not fully masked
                // S^T tile: mfma(A=K, B=Q) -> lane: q=qv, k=kv0+kt*16+lhi*4+r
                f32x4 s[4];
                __builtin_amdgcn_s_setprio(1);
#pragma unroll
                for (int kt = 0; kt < 4; ++kt) {
                    bf16x8 kf0 = *(const bf16x8*)&Kl[kt * 16 + l15][lhi * 8];
                    bf16x8 kf1 = *(const bf16x8*)&Kl[kt * 16 + l15][32 + lhi * 8];
                    f32x4 acc = {};
                    acc = __builtin_amdgcn_mfma_f32_16x16x32_bf16(kf0, qf[0], acc, 0, 0, 0);
                    acc = __builtin_amdgcn_mfma_f32_16x16x32_bf16(kf1, qf[1], acc, 0, 0, 0);
                    s[kt] = acc;
                }
                __builtin_amdgcn_s_setprio(0);

                const bool needmask = (kv0 + 63 > q0);
                if (needmask) {
#pragma unroll
                    for (int kt = 0; kt < 4; ++kt) {
                        const int kb = kv0 + kt * 16 + lhi * 4;
#pragma unroll
                        for (int r = 0; r < 4; ++r)
                            s[kt][r] = (kb + r <= qv) ? s[kt][r] : -1e30f;
                    }
                }
                // row max: in-lane tree + 2 shfl (cross k-quarter)
                f32x4 vm = s[0];
#pragma unroll
                for (int r = 0; r < 4; ++r)
                    vm[r] = fmaxf(fmaxf(s[0][r], s[1][r]), fmaxf(s[2][r], s[3][r]));
                float tmax = fmaxf(fmaxf(vm[0], vm[1]), fmaxf(vm[2], vm[3]));
                tmax = fmaxf(tmax, __shfl_xor(tmax, 16, 64));
                tmax = fmaxf(tmax, __shfl_xor(tmax, 32, 64));

                // defer-max (T13), threshold 8 nats = 11.54 bits
                if (__any(tmax > m2 + 11.5416f)) {
                    const float mnew = fmaxf(m2, tmax);
                    const float corr = exp2f(m2 - mnew);
                    m2 = mnew; l_run *= corr;
                    float cq[4];
#pragma unroll
                    for (int r = 0; r < 4; ++r)
                        cq[r] = __shfl(corr, lhi * 16 + lhi * 4 + r, 64);
#pragma unroll
                    for (int dt = 0; dt < 4; ++dt)
#pragma unroll
                        for (int r = 0; r < 4; ++r) o[dt][r] *= cq[r];
                }
                // exp2 + row sum
                float tsum = 0.f;
#pragma unroll
                for (int kt = 0; kt < 4; ++kt) {
#pragma unroll
                    for (int r = 0; r < 4; ++r) {
                        const float p = exp2f(s[kt][r] - m2);
                        s[kt][r] = p;
                    }
                }
                {
                    f32x4 vs;
#pragma unroll
                    for (int r = 0; r < 4; ++r)
                        vs[r] = (s[0][r] + s[1][r]) + (s[2][r] + s[3][r]);
                    tsum = (vs[0] + vs[1]) + (vs[2] + vs[3]);
                    tsum += __shfl_xor(tsum, 16, 64);
                    tsum += __shfl_xor(tsum, 32, 64);
                    l_run += tsum;
                }
                // pack P into 16x16x16 A-frags (k = lhi*4 + j, j=r)
                bf16x4 pa[4];
#pragma unroll
                for (int kt = 0; kt < 4; ++kt) {
                    unsigned int w0 = cvtpk_bf16(s[kt][0], s[kt][1]);
                    unsigned int w1 = cvtpk_bf16(s[kt][2], s[kt][3]);
                    unsigned int pw[2] = { w0, w1 };
                    pa[kt] = *(const bf16x4*)pw;
                }

                // PV: O += P * V  (16 x K=16 MFMA; B = Vt 8B reads)
                __builtin_amdgcn_s_setprio(1);
#pragma unroll
                for (int dt = 0; dt < 4; ++dt) {
                    const int d = dt * 16 + l15;
                    const int xs = (d >> 3) << 3;
#pragma unroll
                    for (int kt = 0; kt < 4; ++kt) {
                        bf16x4 vb = *(const bf16x4*)&Vt[d][(kt * 16 + lhi * 4) ^ xs];
                        o[dt] = mfma16x16x16(pa[kt], vb, o[dt]);
                    }
                }
                __builtin_amdgcn_s_setprio(0);
            }

            __syncthreads();   // all reads of tile t complete
            if (pf_valid) {
                *(bf16x8*)&Kl[srow][sseg * 8] = pk8;
                const int swz = srow ^ (sseg << 3);
#pragma unroll
                for (int j = 0; j < 8; ++j)
                    Vt[sseg * 8 + j][swz] = (unsigned short)pv8[j];
            }
        }

        // epilogue: fetch l for q = q0 + lhi*4 + r, divide, store
        float rq[4];
#pragma unroll
        for (int r = 0; r < 4; ++r) {
            const float lq = __shfl(l_run, lhi * 16 + lhi * 4 + r, 64);
            rq[r] = 1.0f / lq;
        }
#pragma unroll
        for (int dt = 0; dt < 4; ++dt)
#pragma unroll
            for (int r = 0; r < 4; ++r) {
                const int q = q0 + lhi * 4 + r;
                const int d = dt * 16 + l15;
                Y[((size_t)b * T_ + q) * C_ + h * 64 + d] = f2bf(o[dt][r] * rq[r]);
            }
    }
}

extern "C" void kernel_launch(void* const* d_in, const int* in_sizes, int n_in,
                              void* d_out, int out_size, void* d_ws, size_t ws_size,
                              hipStream_t stream) {
    const float* x     = (const float*)d_in[0];
    const float* Wqkv  = (const float*)d_in[1];
    const float* bqkv  = (const float*)d_in[2];
    const float* Wproj = (const float*)d_in[3];
    const float* bproj = (const float*)d_in[4];
    float* out = (float*)d_out;

    char* ws = (char*)d_ws;
    unsigned short* qkv    = (unsigned short*)(ws);                          // 8192x3072 bf16
    unsigned short* yat    = (unsigned short*)(ws + 50331648);               // 8192x1024 bf16
    unsigned short* WqkvT  = (unsigned short*)(ws + 67108864);               // 3072x1024 bf16
    unsigned short* WprojT = (unsigned short*)(ws + 73400320);               // 1024x1024 bf16
    unsigned short* xb     = (unsigned short*)(ws + 75497472);               // 8192x1024 bf16

    cast_f32_bf16<<<dim3((M_ * C_) / (256 * 8)), dim3(256), 0, stream>>>(x, xb);
    transpose_cast<<<dim3(TC3 / 32, C_ / 32), dim3(256), 0, stream>>>(Wqkv, WqkvT, C_, TC3);
    transpose_cast<<<dim3(C_ / 32, C_ / 32), dim3(256), 0, stream>>>(Wproj, WprojT, C_, C_);
    gemm_bt_bias<false><<<dim3(M_ / 128, TC3 / 128), dim3(256), 0, stream>>>(xb, WqkvT, bqkv, qkv, M_, TC3, C_);
    attn_kernel<<<dim3(B_ * H_, 8), dim3(512), 0, stream>>>(qkv, yat);
    gemm_bt_bias<true><<<dim3(M_ / 128, C_ / 128), dim3(256), 0, stream>>>(yat, WprojT, bproj, out, M_, C_, C_);
}